// Round 8
// baseline (460.954 us; speedup 1.0000x reference)
//
#include <hip/hip_runtime.h>

#define T_STEPS 256
#define BATCH   2048
#define INSZ    65
#define HID     64
#define ROWS    8        // 8 batch rows per block -> 256 blocks = 1 block/CU
#define OUTSZ   7
#define NTH     256      // wave 0: H (whole recurrence), waves 1-3: X (input proj)

typedef __attribute__((ext_vector_type(8))) short bf16x8;  // 8 bf16 = 4 VGPRs
typedef __attribute__((ext_vector_type(4))) float f32x4;

union frag_u { bf16x8 v; unsigned u[4]; };

__device__ __forceinline__ unsigned rne_hi(float f) {   // bf16(RNE) in top 16 bits
    union { float f; unsigned u; } v; v.f = f;
    return v.u + 0x7FFFu + ((v.u >> 16) & 1u);
}
__device__ __forceinline__ short f2bf(float f) { return (short)(rne_hi(f) >> 16); }
__device__ __forceinline__ unsigned pk2(float lo, float hi) {  // [bf16(hi)|bf16(lo)]
    return __builtin_amdgcn_perm(rne_hi(hi), rne_hi(lo), 0x07060302u);
}
__device__ __forceinline__ float bf2f(short s) {
    union { unsigned u; float f; } v; v.u = ((unsigned)(unsigned short)s) << 16;
    return v.f;
}
__device__ __forceinline__ float sigm(float x) {
    return __builtin_amdgcn_rcpf(1.0f + __expf(-x));
}
__device__ __forceinline__ float tanh_f(float x) {
    return 1.0f - 2.0f * __builtin_amdgcn_rcpf(__expf(2.0f * x) + 1.0f);
}
__device__ __forceinline__ void bump(int* f, int lane) {
    __threadfence_block();                  // lgkm-only drain; vmcnt untouched
    if (lane == 0) atomicAdd(f, 1);
}
__device__ __forceinline__ void spin_ge(const int* f, int tgt) {
    while (*(volatile const int*)f < tgt) {}   // wave is alone on its SIMD
    __threadfence_block();
}

// LDS: P ring, 4 slots x 16KB: slot s, tile n, lane -> P[s*4096 + n*256 + lane*4] (f32x4, raw C-frag)
//      h: 2 parities x 512 shorts, frag-major: (row,k) @ (k>>3)*64 + row*8 + (k&7)

__global__ __launch_bounds__(NTH, 1)
void lstm_fused(const float* __restrict__ x,    const float* __restrict__ W_ih,
                const float* __restrict__ W_hh, const float* __restrict__ b_ih,
                const float* __restrict__ b_hh, const float* __restrict__ fc_W,
                const float* __restrict__ fc_b, float* __restrict__ out)
{
    __shared__ __align__(16) float P[4 * 4096];
    __shared__ __align__(16) short hb[2 * 512];
    __shared__ int flg[2];                  // [0]=pr (X bumps, 3/step), [1]=cons (H bumps, 1/step)

    const int tid   = threadIdx.x;
    const int wid   = tid >> 6;
    const int lane  = tid & 63;
    const int quad  = lane >> 4;
    const int col16 = lane & 15;
    const int b0    = blockIdx.x * ROWS;

    if (tid == 0) { flg[0] = 0; flg[1] = 0; }
    for (int i = tid; i < 1024; i += NTH) hb[i] = 0;     // h(-1) = 0 both parities
    __syncthreads();

    if (wid == 0) {
        // ===================== H: full recurrence, one wave, zero barriers =====================
#if __has_builtin(__builtin_amdgcn_s_setprio)
        __builtin_amdgcn_s_setprio(1);
#endif
        bf16x8 wfh[16][2];                  // W_hh B-frags, tile n = gate*4 + tt
        #pragma unroll
        for (int n = 0; n < 16; ++n) {
            const int wr = (n >> 2) * 64 + (n & 3) * 16 + col16;
            #pragma unroll
            for (int kc = 0; kc < 2; ++kc) {
                bf16x8 f;
                #pragma unroll
                for (int j = 0; j < 8; ++j)
                    f[j] = f2bf(W_hh[wr * HID + kc * 32 + quad * 8 + j]);
                wfh[n][kc] = f;
            }
        }
        const int tth = (quad >> 1) * 2;            // this lane activates tt in {tth, tth+1}
        const int hrd = quad * 64 + (lane & 7) * 8; // h A-frag read base (+kc*256)
        float c[2][4] = {{0.f,0.f,0.f,0.f},{0.f,0.f,0.f,0.f}};

        for (int t = 0; t < T_STEPS; ++t) {
            const int par = t & 1;
            const short* hr = &hb[(par ^ 1) * 512];
            const bf16x8 h0 = *(const bf16x8*)&hr[hrd];
            const bf16x8 h1 = *(const bf16x8*)&hr[hrd + 256];
            if ((t & 1) == 0) spin_ge(&flg[0], 3 * (t + 2));   // P(t),P(t+1) ready (X is ~2+ ahead)
            const float* ps = &P[(t & 3) * 4096 + lane * 4];

            f32x4 acc[16];
            static constexpr int ttord[4] = {0, 2, 1, 3};      // unlock s=0 activations early
            #pragma unroll
            for (int gi = 0; gi < 4; ++gi) {
                const int tt = ttord[gi];
                #pragma unroll
                for (int g = 0; g < 4; ++g) {
                    const int n = g * 4 + tt;
                    f32x4 p = *(const f32x4*)&ps[n * 256];      // C-init = bias + x.W_ih
                    p = __builtin_amdgcn_mfma_f32_16x16x32_bf16(h0, wfh[n][0], p, 0, 0, 0);
                    acc[n] = __builtin_amdgcn_mfma_f32_16x16x32_bf16(h1, wfh[n][1], p, 0, 0, 0);
                }
            }
            bump(&flg[1], lane);                               // P(t) consumed

            // activations: lane owns rows {(quad&1)*4 + r}, cols {(tth+s)*16 + col16}
            const bool up = (quad >= 2);
            short* hw = &hb[par * 512];
            #pragma unroll
            for (int s = 0; s < 2; ++s) {
                #pragma unroll
                for (int r = 0; r < 4; ++r) {
                    const float gv_i = up ? acc[0 + 2 + s][r]  : acc[0 + s][r];
                    const float gv_f = up ? acc[4 + 2 + s][r]  : acc[4 + s][r];
                    const float gv_g = up ? acc[8 + 2 + s][r]  : acc[8 + s][r];
                    const float gv_o = up ? acc[12 + 2 + s][r] : acc[12 + s][r];
                    const float ig = sigm(gv_i), fg = sigm(gv_f);
                    const float gg = tanh_f(gv_g), og = sigm(gv_o);
                    c[s][r] = fg * c[s][r] + ig * gg;
                    const float h = og * tanh_f(c[s][r]);
                    const int row = (quad & 1) * 4 + r;
                    const int col = (tth + s) * 16 + col16;
                    hw[(col >> 3) * 64 + row * 8 + (col & 7)] = f2bf(h);
                }
            }
        }
    } else {
        // ===================== X: input projection, self-paced, 2-3 steps ahead =====================
        const int xw  = wid - 1;                     // 0..2; tiles n = xw + 3*i
        const int cnt = (xw == 0) ? 6 : 5;
        bf16x8 wfx[6][2]; f32x4 biasv[6]; float wlc[6];
        #pragma unroll
        for (int i = 0; i < 6; ++i) {
            if (i >= cnt) continue;
            const int n  = xw + 3 * i;
            const int wr = (n >> 2) * 64 + (n & 3) * 16 + col16;
            #pragma unroll
            for (int kc = 0; kc < 2; ++kc) {
                bf16x8 f;
                #pragma unroll
                for (int j = 0; j < 8; ++j)
                    f[j] = f2bf(W_ih[wr * INSZ + kc * 32 + quad * 8 + j]);
                wfx[i][kc] = f;
            }
            wlc[i] = W_ih[wr * INSZ + 64];           // k=64 rank-1 column
            const float bv = b_ih[wr] + b_hh[wr];
            biasv[i] = (f32x4){bv, bv, bv, bv};
        }
        // A-frag globals: lane covers (row = lane&7, k = quad*8+j [+32]); fixup rows (quad*4+r)&7
        const float* xr = x + (size_t)(b0 + (lane & 7)) * T_STEPS * INSZ + quad * 8;
        const float* p64[4];
        #pragma unroll
        for (int r = 0; r < 4; ++r)
            p64[r] = x + (size_t)(b0 + ((quad * 4 + r) & 7)) * T_STEPS * INSZ + 64;

        float xf[16], x64v[4];
        #pragma unroll
        for (int j = 0; j < 8; ++j) { xf[j] = xr[j]; xf[8 + j] = xr[32 + j]; }
        #pragma unroll
        for (int r = 0; r < 4; ++r) x64v[r] = p64[r][0];

        for (int t = 0; t < T_STEPS; ++t) {
            const int tn = (t + 1 < 255) ? (t + 1) : 255;      // prefetch next step
            float nf[16], n64[4];
            #pragma unroll
            for (int j = 0; j < 8; ++j) {
                nf[j]     = xr[tn * INSZ + j];
                nf[8 + j] = xr[tn * INSZ + 32 + j];
            }
            #pragma unroll
            for (int r = 0; r < 4; ++r) n64[r] = p64[r][tn * INSZ];

            frag_u A0, A1;
            #pragma unroll
            for (int d = 0; d < 4; ++d) {
                A0.u[d] = pk2(xf[2 * d],     xf[2 * d + 1]);
                A1.u[d] = pk2(xf[8 + 2 * d], xf[8 + 2 * d + 1]);
            }
            if (t >= 4) spin_ge(&flg[1], t - 3);               // ring slot free (H consumed t-4)
            float* pw = &P[(t & 3) * 4096 + lane * 4];
            #pragma unroll
            for (int i = 0; i < 6; ++i) {
                if (i >= cnt) continue;
                const int n = xw + 3 * i;
                f32x4 p = __builtin_amdgcn_mfma_f32_16x16x32_bf16(A0.v, wfx[i][0], biasv[i], 0, 0, 0);
                p = __builtin_amdgcn_mfma_f32_16x16x32_bf16(A1.v, wfx[i][1], p, 0, 0, 0);
                #pragma unroll
                for (int r = 0; r < 4; ++r)                     // k=64 rank-1 fixup
                    p[r] = __builtin_fmaf(wlc[i], x64v[r], p[r]);
                *(f32x4*)&pw[n * 256] = p;
            }
            bump(&flg[0], lane);                                // this wave's tiles of P(t) ready
            #pragma unroll
            for (int j = 0; j < 16; ++j) xf[j] = nf[j];
            #pragma unroll
            for (int r = 0; r < 4; ++r) x64v[r] = n64[r];
        }
    }
    __syncthreads();

    // ---- FC(64->7) + sigmoid; h(255) in parity-1 slot ----
    if (tid < ROWS * OUTSZ) {
        const int m = tid & 7;
        const int o = tid >> 3;
        float s = fc_b[o];
        #pragma unroll
        for (int k = 0; k < HID; ++k)
            s += bf2f(hb[512 + (k >> 3) * 64 + m * 8 + (k & 7)]) * fc_W[o * HID + k];
        out[(size_t)(b0 + m) * OUTSZ + o] = sigm(s);
    }
}

extern "C" void kernel_launch(void* const* d_in, const int* in_sizes, int n_in,
                              void* d_out, int out_size, void* d_ws, size_t ws_size,
                              hipStream_t stream) {
    const float* x    = (const float*)d_in[0];
    const float* W_ih = (const float*)d_in[1];
    const float* W_hh = (const float*)d_in[2];
    const float* b_ih = (const float*)d_in[3];
    const float* b_hh = (const float*)d_in[4];
    const float* fc_W = (const float*)d_in[5];
    const float* fc_b = (const float*)d_in[6];
    float* out = (float*)d_out;

    dim3 grid(BATCH / ROWS);    // 256 blocks -> 1 per CU
    dim3 block(NTH);            // 4 waves: 1 H (SIMD0) + 3 X — one wave per SIMD
    hipLaunchKernelGGL(lstm_fused, grid, block, 0, stream,
                       x, W_ih, W_hh, b_ih, b_hh, fc_W, fc_b, out);
}